// Round 20
// baseline (262.514 us; speedup 1.0000x reference)
//
#include <hip/hip_runtime.h>
#include <math.h>

#define EPT 16
#define CHUNK (256 * EPT)  // 4096 edges per scatter block
#define CAP 12288          // fixed bucket segment capacity (mean 8192, +45 sigma)

typedef __attribute__((ext_vector_type(8))) short s16x8;
typedef __attribute__((ext_vector_type(4))) float f32x4;

__device__ inline unsigned short f2bf(float f) {  // RNE float->bf16
    unsigned u = __builtin_bit_cast(unsigned, f);
    u += 0x7fffu + ((u >> 16) & 1u);
    return (unsigned short)(u >> 16);
}
__device__ inline float bf2f(unsigned short h) {
    unsigned u = ((unsigned)h) << 16;
    return __builtin_bit_cast(float, u);
}

// ====== prep: bucket scatter (blocks < SB) + W1 bf16-split frag pack (rest) ======
// Bucket b = nodes [256b, 256(b+1)); segment [b*CAP, b*CAP + bfill[b]).
// B frag (16x16x32): lane = (col&15) + ((k&31)>>3)*16, i = k&7;
// W1 idx = ((ct*8 + ks)*64 + lane)*8 + i  (ct=col>>4, ks=k>>5).

__global__ void prep_k(const int* __restrict__ src, const int* __restrict__ dst,
                       int* __restrict__ bfill, unsigned int* __restrict__ bpk, int E, int SB,
                       const float* __restrict__ W1,
                       unsigned short* __restrict__ w1h, unsigned short* __restrict__ w1l) {
    __shared__ int hist[256], gofs[256], lfill[256];
    int t = threadIdx.x;
    if (blockIdx.x >= SB) {  // ---- W1 pack branch (32768 elems, 128 blocks) ----
        int e = (blockIdx.x - SB) * 256 + t;
        int k = e >> 7, col = e & 127;
        float w = W1[e];
        unsigned short h = f2bf(w), l = f2bf(w - bf2f(h));
        int ct = col >> 4, ks = k >> 5;
        int la = (col & 15) + (((k >> 3) & 3) << 4);
        int i = k & 7;
        size_t idx = ((((size_t)ct * 8 + ks) * 64 + la) << 3) + i;
        w1h[idx] = h;
        w1l[idx] = l;
        return;
    }
    // ---- scatter branch ----
    int base = blockIdx.x * CHUNK;
    hist[t] = 0;
    lfill[t] = 0;
    __syncthreads();
    int ds[EPT], ss[EPT];
#pragma unroll
    for (int i = 0; i < EPT; ++i) {
        int e = base + i * 256 + t;
        if (e < E) {
            ds[i] = dst[e];
            ss[i] = src[e];
            atomicAdd(&hist[ds[i] >> 8], 1);
        } else {
            ds[i] = -1;
        }
    }
    __syncthreads();
    if (hist[t]) gofs[t] = atomicAdd(&bfill[t], hist[t]);
    __syncthreads();
#pragma unroll
    for (int i = 0; i < EPT; ++i) {
        if (ds[i] >= 0) {
            int b = ds[i] >> 8;
            int p = atomicAdd(&lfill[b], 1);
            int idx = gofs[b] + p;
            if (idx < CAP)
                bpk[b * CAP + idx] = ((unsigned)(ds[i] & 255) << 16) | (unsigned)ss[i];
        }
    }
}

// ====== bucket build: deg/dinv/rbeg/rend + degree-sorted perm + csr counting-sort ======

__global__ void bucket_build_k(const unsigned int* __restrict__ bpk,
                               const int* __restrict__ bfill,
                               unsigned short* __restrict__ csr,
                               int* __restrict__ rbeg, int* __restrict__ rend,
                               float* __restrict__ dinv, unsigned short* __restrict__ perm,
                               int n) {
    __shared__ int hist[256], loff[256], lfill[256], tmp[256];
    __shared__ int h2[64];
    __shared__ unsigned short scsr[CAP];
    int b = blockIdx.x, t = threadIdx.x;
    int base = b * CAP;
    int bsize = min(bfill[b], CAP);
    hist[t] = 0;
    lfill[t] = 0;
    if (t < 64) h2[t] = 0;
    __syncthreads();
    for (int idx = t; idx < bsize; idx += 256)
        atomicAdd(&hist[bpk[base + idx] >> 16], 1);
    __syncthreads();
    int deg = hist[t];
    tmp[t] = deg;
    __syncthreads();
    for (int off = 1; off < 256; off <<= 1) {
        int a = (t >= off) ? tmp[t - off] : 0;
        __syncthreads();
        tmp[t] += a;
        __syncthreads();
    }
    loff[t] = tmp[t] - deg;  // exclusive
    int node = (b << 8) + t;
    int dc = min(deg, 63);
    if (node < n) {
        rbeg[node] = base + loff[t];
        rend[node] = base + loff[t] + deg;
        dinv[node] = rsqrtf((float)(deg + 1));  // +1 self-loop
        atomicAdd(&h2[dc], 1);
    }
    perm[(b << 8) + t] = 0xFFFFu;  // sentinel (slots >= count stay sentinel)
    __syncthreads();
    if (t == 0) {  // exclusive scan of 64 degree bins
        int s = 0;
#pragma unroll
        for (int i2 = 0; i2 < 64; ++i2) {
            int v = h2[i2];
            h2[i2] = s;
            s += v;
        }
    }
    __syncthreads();
    if (node < n) {
        int rank = atomicAdd(&h2[dc], 1);
        perm[(b << 8) + rank] = (unsigned short)node;
    }
    __syncthreads();
    for (int idx = t; idx < bsize; idx += 256) {
        unsigned u = bpk[base + idx];
        int ln = (int)(u >> 16);
        int sp = atomicAdd(&lfill[ln], 1);
        scsr[loff[ln] + sp] = (unsigned short)(u & 0xFFFFu);
    }
    __syncthreads();
    for (int idx = t; idx < bsize; idx += 256)
        csr[base + idx] = scsr[idx];
}

// ====== GEMM1 via MFMA bf16x3: hs[n,128] = (x @ W1) * dinv (round-18 verified) ======

__global__ __launch_bounds__(256) void gemm1_k(const float* __restrict__ x,
                                               const unsigned short* __restrict__ wh,
                                               const unsigned short* __restrict__ wl,
                                               const float* __restrict__ dinv,
                                               float* __restrict__ hs, int n) {
    __shared__ __align__(16) unsigned short ah[2 * 8 * 64 * 8];  // 16 KB
    __shared__ __align__(16) unsigned short al[2 * 8 * 64 * 8];  // 16 KB
    __shared__ __align__(16) unsigned short bh[8 * 64 * 8];      // 8 KB
    __shared__ __align__(16) unsigned short bl[8 * 64 * 8];      // 8 KB
    int tid = threadIdx.x;
    int wave = tid >> 6, lane = tid & 63;
    int band = wave & 1, cq = wave >> 1;
    int r0 = blockIdx.x * 32;

    for (int v = tid; v < 2048; v += 256) {
        int r = v >> 6;
        int k = (v & 63) << 2;
        int row = r0 + r;
        if (row >= n) row = n - 1;
        float4 xv = *(const float4*)(x + (long long)row * 256 + k);
        int bd = r >> 4, ks = k >> 5;
        int la = (r & 15) + (((k >> 3) & 3) << 4);
        int i0 = k & 7;
        size_t idx = ((((size_t)bd * 8 + ks) * 64 + la) << 3) + i0;
        ushort4 hh, ll;
        hh.x = f2bf(xv.x); ll.x = f2bf(xv.x - bf2f(hh.x));
        hh.y = f2bf(xv.y); ll.y = f2bf(xv.y - bf2f(hh.y));
        hh.z = f2bf(xv.z); ll.z = f2bf(xv.z - bf2f(hh.z));
        hh.w = f2bf(xv.w); ll.w = f2bf(xv.w - bf2f(hh.w));
        *(ushort4*)&ah[idx] = hh;
        *(ushort4*)&al[idx] = ll;
    }

    f32x4 acc[4];
#pragma unroll
    for (int c = 0; c < 4; ++c) acc[c] = (f32x4){0.f, 0.f, 0.f, 0.f};

    const float4* gh = (const float4*)wh;
    const float4* gl = (const float4*)wl;
    for (int ks = 0; ks < 8; ++ks) {
        __syncthreads();
#pragma unroll
        for (int it = 0; it < 2; ++it) {
            int s = it * 256 + tid;
            size_t gi = ((size_t)(s >> 6) * 8 + ks) * 64 + (s & 63);
            ((float4*)bh)[s] = gh[gi];
            ((float4*)bl)[s] = gl[gi];
        }
        __syncthreads();
        size_t aidx = (((size_t)band * 8 + ks) * 64 + lane) << 3;
        s16x8 Ah = *(const s16x8*)&ah[aidx];
        s16x8 Al = *(const s16x8*)&al[aidx];
#pragma unroll
        for (int c = 0; c < 4; ++c) {
            int ct = cq * 4 + c;
            size_t bidx = (((size_t)ct) * 64 + lane) << 3;
            s16x8 Bh = *(const s16x8*)&bh[bidx];
            s16x8 Bl = *(const s16x8*)&bl[bidx];
            acc[c] = __builtin_amdgcn_mfma_f32_16x16x32_bf16(Ah, Bh, acc[c], 0, 0, 0);
            acc[c] = __builtin_amdgcn_mfma_f32_16x16x32_bf16(Ah, Bl, acc[c], 0, 0, 0);
            acc[c] = __builtin_amdgcn_mfma_f32_16x16x32_bf16(Al, Bh, acc[c], 0, 0, 0);
        }
    }

    int colb = cq * 64 + (lane & 15);
    int rbase = r0 + band * 16 + ((lane >> 4) << 2);
#pragma unroll
    for (int reg = 0; reg < 4; ++reg) {
        int row = rbase + reg;
        if (row < n) {
            float di = dinv[row];
#pragma unroll
            for (int c = 0; c < 4; ++c)
                hs[(long long)row * 128 + colb + c * 16] = acc[c][reg] * di;
        }
    }
}

// ====== GEMM2 (fp32, known-good): hs2[n,64] = (h1 @ W2) * dinv ======
// Logits are threshold-critical -> keep full fp32 path here.

__global__ __launch_bounds__(128) void gemm2_k(const float* __restrict__ h1,
                                               const float* __restrict__ W,
                                               const float* __restrict__ dinv,
                                               float* __restrict__ hs2, int n) {
    __shared__ float xs[32][64];  // 8 KB
    int tid = threadIdx.x;
    int cg = tid & 15;   // cols cg*4 .. +3  (64 cols)
    int rg = tid >> 4;   // rows rg*4 .. +3  (32 rows)
    int r0 = blockIdx.x * 32;
    float acc[4][4];
#pragma unroll
    for (int r = 0; r < 4; ++r)
#pragma unroll
        for (int c = 0; c < 4; ++c) acc[r][c] = 0.0f;

    for (int kc = 0; kc < 2; ++kc) {  // 2 chunks of 64 k
        __syncthreads();
        for (int v = tid; v < 32 * 16; v += 128) {
            int r = v >> 4;
            int k4 = v & 15;
            float4 val = make_float4(0.f, 0.f, 0.f, 0.f);
            int row = r0 + r;
            if (row < n) val = *(const float4*)(h1 + (long long)row * 128 + kc * 64 + k4 * 4);
            *(float4*)&xs[r][k4 * 4] = val;
        }
        __syncthreads();
        const float* Wp = W + (long long)(kc * 64) * 64 + cg * 4;
#pragma unroll 4
        for (int k4 = 0; k4 < 16; ++k4) {
            float4 w0 = *(const float4*)(Wp + (k4 * 4 + 0) * 64);
            float4 w1 = *(const float4*)(Wp + (k4 * 4 + 1) * 64);
            float4 w2 = *(const float4*)(Wp + (k4 * 4 + 2) * 64);
            float4 w3 = *(const float4*)(Wp + (k4 * 4 + 3) * 64);
#pragma unroll
            for (int r = 0; r < 4; ++r) {
                float4 xv = *(const float4*)&xs[rg * 4 + r][k4 * 4];
                acc[r][0] += xv.x * w0.x + xv.y * w1.x + xv.z * w2.x + xv.w * w3.x;
                acc[r][1] += xv.x * w0.y + xv.y * w1.y + xv.z * w2.y + xv.w * w3.y;
                acc[r][2] += xv.x * w0.z + xv.y * w1.z + xv.z * w2.z + xv.w * w3.z;
                acc[r][3] += xv.x * w0.w + xv.y * w1.w + xv.z * w2.w + xv.w * w3.w;
            }
        }
    }
#pragma unroll
    for (int r = 0; r < 4; ++r) {
        int row = r0 + rg * 4 + r;
        if (row < n) {
            float di = dinv[row];
            float4 o = make_float4(acc[r][0] * di, acc[r][1] * di,
                                   acc[r][2] * di, acc[r][3] * di);
            *(float4*)(hs2 + (long long)row * 64 + cg * 4) = o;
        }
    }
}

// ====== channel-split gathers, merged dispatch, degree-sorted node order ======
// perm changes only wave->node scheduling; per-node arithmetic identical.

__global__ void gather1p_k(const float* __restrict__ hs, const int* __restrict__ rbeg,
                           const int* __restrict__ rend, const unsigned short* __restrict__ csr,
                           const unsigned short* __restrict__ perm,
                           const float* __restrict__ dinv, const float* __restrict__ b1,
                           float* __restrict__ h1, int n, int gblk) {
    int pass = blockIdx.x / gblk;
    int blk = blockIdx.x - pass * gblk;
    int c0 = pass * 32;
    int g = threadIdx.x >> 3;
    int lane = threadIdx.x & 7;
    int i = perm[blk * 32 + g];
    if (i >= n) return;  // sentinel / tail
    const float* hsc = hs + c0;
    float4 acc = ((const float4*)(hsc + (long long)i * 128))[lane];  // self term
    int beg = rbeg[i], end = rend[i];
    int j = beg;
    for (; j + 8 <= end; j += 8) {
        int s0 = csr[j], s1 = csr[j + 1], s2 = csr[j + 2], s3 = csr[j + 3];
        int s4 = csr[j + 4], s5 = csr[j + 5], s6 = csr[j + 6], s7 = csr[j + 7];
        float4 v0 = ((const float4*)(hsc + (long long)s0 * 128))[lane];
        float4 v1 = ((const float4*)(hsc + (long long)s1 * 128))[lane];
        float4 v2 = ((const float4*)(hsc + (long long)s2 * 128))[lane];
        float4 v3 = ((const float4*)(hsc + (long long)s3 * 128))[lane];
        float4 v4 = ((const float4*)(hsc + (long long)s4 * 128))[lane];
        float4 v5 = ((const float4*)(hsc + (long long)s5 * 128))[lane];
        float4 v6 = ((const float4*)(hsc + (long long)s6 * 128))[lane];
        float4 v7 = ((const float4*)(hsc + (long long)s7 * 128))[lane];
        acc.x += (v0.x + v1.x + v2.x + v3.x) + (v4.x + v5.x + v6.x + v7.x);
        acc.y += (v0.y + v1.y + v2.y + v3.y) + (v4.y + v5.y + v6.y + v7.y);
        acc.z += (v0.z + v1.z + v2.z + v3.z) + (v4.z + v5.z + v6.z + v7.z);
        acc.w += (v0.w + v1.w + v2.w + v3.w) + (v4.w + v5.w + v6.w + v7.w);
    }
    for (; j < end; ++j) {
        int s0 = csr[j];
        float4 v0 = ((const float4*)(hsc + (long long)s0 * 128))[lane];
        acc.x += v0.x; acc.y += v0.y; acc.z += v0.z; acc.w += v0.w;
    }
    float di = dinv[i];
    float4 bb = ((const float4*)(b1 + c0))[lane];
    float4 o;
    o.x = fmaxf(di * acc.x + bb.x, 0.0f);
    o.y = fmaxf(di * acc.y + bb.y, 0.0f);
    o.z = fmaxf(di * acc.z + bb.z, 0.0f);
    o.w = fmaxf(di * acc.w + bb.w, 0.0f);
    ((float4*)(h1 + (long long)i * 128 + c0))[lane] = o;
}

__global__ void gather2p_k(const float* __restrict__ hs2, const int* __restrict__ rbeg,
                           const int* __restrict__ rend, const unsigned short* __restrict__ csr,
                           const unsigned short* __restrict__ perm,
                           const float* __restrict__ dinv, const float* __restrict__ b2,
                           float* __restrict__ out, int n, int gblk) {
    int pass = blockIdx.x / gblk;
    int blk = blockIdx.x - pass * gblk;
    int c0 = pass * 32;
    int g = threadIdx.x >> 3;
    int lane = threadIdx.x & 7;
    int i = perm[blk * 32 + g];
    if (i >= n) return;
    const float* hc = hs2 + c0;
    float4 acc = ((const float4*)(hc + (long long)i * 64))[lane];  // self term
    int beg = rbeg[i], end = rend[i];
    int j = beg;
    for (; j + 8 <= end; j += 8) {
        int s0 = csr[j], s1 = csr[j + 1], s2 = csr[j + 2], s3 = csr[j + 3];
        int s4 = csr[j + 4], s5 = csr[j + 5], s6 = csr[j + 6], s7 = csr[j + 7];
        float4 v0 = ((const float4*)(hc + (long long)s0 * 64))[lane];
        float4 v1 = ((const float4*)(hc + (long long)s1 * 64))[lane];
        float4 v2 = ((const float4*)(hc + (long long)s2 * 64))[lane];
        float4 v3 = ((const float4*)(hc + (long long)s3 * 64))[lane];
        float4 v4 = ((const float4*)(hc + (long long)s4 * 64))[lane];
        float4 v5 = ((const float4*)(hc + (long long)s5 * 64))[lane];
        float4 v6 = ((const float4*)(hc + (long long)s6 * 64))[lane];
        float4 v7 = ((const float4*)(hc + (long long)s7 * 64))[lane];
        acc.x += (v0.x + v1.x + v2.x + v3.x) + (v4.x + v5.x + v6.x + v7.x);
        acc.y += (v0.y + v1.y + v2.y + v3.y) + (v4.y + v5.y + v6.y + v7.y);
        acc.z += (v0.z + v1.z + v2.z + v3.z) + (v4.z + v5.z + v6.z + v7.z);
        acc.w += (v0.w + v1.w + v2.w + v3.w) + (v4.w + v5.w + v6.w + v7.w);
    }
    for (; j < end; ++j) {
        int s0 = csr[j];
        float4 v0 = ((const float4*)(hc + (long long)s0 * 64))[lane];
        acc.x += v0.x; acc.y += v0.y; acc.z += v0.z; acc.w += v0.w;
    }
    float di = dinv[i];
    float4 bb = ((const float4*)(b2 + c0))[lane];
    float lx = di * acc.x + bb.x;
    float ly = di * acc.y + bb.y;
    float lz = di * acc.z + bb.z;
    float lw = di * acc.w + bb.w;
    float4 p;
    p.x = 1.0f / (1.0f + expf(-lx));
    p.y = 1.0f / (1.0f + expf(-ly));
    p.z = 1.0f / (1.0f + expf(-lz));
    p.w = 1.0f / (1.0f + expf(-lw));
    long long total = (long long)n * 64;
    long long o0 = (long long)i * 64 + c0 + lane * 4;
    float4 pr;
    pr.x = (p.x > 0.5f) ? 1.0f : 0.0f;
    pr.y = (p.y > 0.5f) ? 1.0f : 0.0f;
    pr.z = (p.z > 0.5f) ? 1.0f : 0.0f;
    pr.w = (p.w > 0.5f) ? 1.0f : 0.0f;
    *(float4*)(out + o0) = pr;
    *(float4*)(out + total + o0) = p;
}

// ================= launch =================

extern "C" void kernel_launch(void* const* d_in, const int* in_sizes, int n_in,
                              void* d_out, int out_size, void* d_ws, size_t ws_size,
                              hipStream_t stream) {
    const float* x  = (const float*)d_in[0];
    const int*   ei = (const int*)d_in[1];
    const float* W1 = (const float*)d_in[2];
    const float* b1 = (const float*)d_in[3];
    const float* W2 = (const float*)d_in[4];
    const float* b2 = (const float*)d_in[5];
    float* out = (float*)d_out;

    const int n = in_sizes[0] / 256;   // 50000 (packing requires n < 65536)
    const int E = in_sizes[1] / 2;     // 1.6M
    const int* src = ei;
    const int* dst = ei + E;
    const int nb = (n + 255) / 256;    // bucket count (196)

    // ---- workspace carve-up (256B-aligned) ----
    char* base = (char*)d_ws;
    size_t off = 0;
    auto carve = [&](size_t bytes) -> void* {
        void* p = base + off;
        off = (off + bytes + 255) & ~(size_t)255;
        return p;
    };
    int*   bfill = (int*)  carve(256 * sizeof(int));
    unsigned short* csr = (unsigned short*)carve((size_t)nb * CAP * sizeof(unsigned short));
    int*   rbeg  = (int*)  carve((size_t)n * sizeof(int));
    int*   rend  = (int*)  carve((size_t)n * sizeof(int));
    float* dinv  = (float*)carve((size_t)n * sizeof(float));
    unsigned short* perm = (unsigned short*)carve((size_t)nb * 256 * sizeof(unsigned short));
    unsigned short* w1h = (unsigned short*)carve(32768 * sizeof(unsigned short));
    unsigned short* w1l = (unsigned short*)carve(32768 * sizeof(unsigned short));
    float* hs0   = (float*)carve((size_t)n * 128 * sizeof(float));
    float* h1    = (float*)carve((size_t)n * 128 * sizeof(float));
    float* hs2   = (float*)carve((size_t)n * 64 * sizeof(float));
    // packed bucket buffer aliases hs0 (nb*CAP*4B = 9.6MB <= 25.6MB);
    // consumed by bucket_build_k before gemm1_k writes hs0 (same stream, sequential)
    unsigned int* bpk = (unsigned int*)hs0;

    const int SB = (E + CHUNK - 1) / CHUNK;  // scatter blocks (391)
    const int PB = 32768 / 256;              // W1 pack blocks (128)

    hipMemsetAsync(bfill, 0, 256 * sizeof(int), stream);
    prep_k<<<SB + PB, 256, 0, stream>>>(src, dst, bfill, bpk, E, SB, W1, w1h, w1l);
    bucket_build_k<<<nb, 256, 0, stream>>>(bpk, bfill, csr, rbeg, rend, dinv, perm, n);

    gemm1_k<<<(n + 31) / 32, 256, 0, stream>>>(x, w1h, w1l, dinv, hs0, n);

    const int gblk = nb * 8;  // 32 perm-slots per block over nb*256 slots
    gather1p_k<<<4 * gblk, 256, 0, stream>>>(hs0, rbeg, rend, csr, perm, dinv, b1, h1, n, gblk);

    gemm2_k<<<(n + 31) / 32, 128, 0, stream>>>(h1, W2, dinv, hs2, n);

    gather2p_k<<<2 * gblk, 256, 0, stream>>>(hs2, rbeg, rend, csr, perm, dinv, b2, out, n, gblk);
}

// Round 21
// 228.586 us; speedup vs baseline: 1.1484x; 1.1484x over previous
//
#include <hip/hip_runtime.h>
#include <math.h>

#define EPT 16
#define CHUNK (256 * EPT)  // 4096 edges per scatter block
#define CAP 12288          // fixed bucket segment capacity (mean 8192, +45 sigma)

typedef __attribute__((ext_vector_type(8))) short s16x8;
typedef __attribute__((ext_vector_type(4))) float f32x4;

__device__ inline unsigned short f2bf(float f) {  // RNE float->bf16
    unsigned u = __builtin_bit_cast(unsigned, f);
    u += 0x7fffu + ((u >> 16) & 1u);
    return (unsigned short)(u >> 16);
}
__device__ inline float bf2f(unsigned short h) {
    unsigned u = ((unsigned)h) << 16;
    return __builtin_bit_cast(float, u);
}

// ====== prep: bucket scatter (blocks < SB) + W1 bf16-split frag pack (rest) ======
// Bucket b = nodes [256b, 256(b+1)); segment [b*CAP, b*CAP + bfill[b]).
// B frag (16x16x32): lane = (col&15) + ((k&31)>>3)*16, i = k&7;
// W1 idx = ((ct*8 + ks)*64 + lane)*8 + i  (ct=col>>4, ks=k>>5).

__global__ void prep_k(const int* __restrict__ src, const int* __restrict__ dst,
                       int* __restrict__ bfill, unsigned int* __restrict__ bpk, int E, int SB,
                       const float* __restrict__ W1,
                       unsigned short* __restrict__ w1h, unsigned short* __restrict__ w1l) {
    __shared__ int hist[256], gofs[256], lfill[256];
    int t = threadIdx.x;
    if (blockIdx.x >= SB) {  // ---- W1 pack branch (32768 elems, 128 blocks) ----
        int e = (blockIdx.x - SB) * 256 + t;
        int k = e >> 7, col = e & 127;
        float w = W1[e];
        unsigned short h = f2bf(w), l = f2bf(w - bf2f(h));
        int ct = col >> 4, ks = k >> 5;
        int la = (col & 15) + (((k >> 3) & 3) << 4);
        int i = k & 7;
        size_t idx = ((((size_t)ct * 8 + ks) * 64 + la) << 3) + i;
        w1h[idx] = h;
        w1l[idx] = l;
        return;
    }
    // ---- scatter branch ----
    int base = blockIdx.x * CHUNK;
    hist[t] = 0;
    lfill[t] = 0;
    __syncthreads();
    int ds[EPT], ss[EPT];
#pragma unroll
    for (int i = 0; i < EPT; ++i) {
        int e = base + i * 256 + t;
        if (e < E) {
            ds[i] = dst[e];
            ss[i] = src[e];
            atomicAdd(&hist[ds[i] >> 8], 1);
        } else {
            ds[i] = -1;
        }
    }
    __syncthreads();
    if (hist[t]) gofs[t] = atomicAdd(&bfill[t], hist[t]);
    __syncthreads();
#pragma unroll
    for (int i = 0; i < EPT; ++i) {
        if (ds[i] >= 0) {
            int b = ds[i] >> 8;
            int p = atomicAdd(&lfill[b], 1);
            int idx = gofs[b] + p;
            if (idx < CAP)
                bpk[b * CAP + idx] = ((unsigned)(ds[i] & 255) << 16) | (unsigned)ss[i];
        }
    }
}

// ====== bucket build: deg/dinv/rbeg/rend + csr counting-sort ======

__global__ void bucket_build_k(const unsigned int* __restrict__ bpk,
                               const int* __restrict__ bfill,
                               unsigned short* __restrict__ csr,
                               int* __restrict__ rbeg, int* __restrict__ rend,
                               float* __restrict__ dinv, int n) {
    __shared__ int hist[256], loff[256], lfill[256], tmp[256];
    __shared__ unsigned short scsr[CAP];
    int b = blockIdx.x, t = threadIdx.x;
    int base = b * CAP;
    int bsize = min(bfill[b], CAP);
    hist[t] = 0;
    lfill[t] = 0;
    __syncthreads();
    for (int idx = t; idx < bsize; idx += 256)
        atomicAdd(&hist[bpk[base + idx] >> 16], 1);
    __syncthreads();
    int deg = hist[t];
    tmp[t] = deg;
    __syncthreads();
    for (int off = 1; off < 256; off <<= 1) {
        int a = (t >= off) ? tmp[t - off] : 0;
        __syncthreads();
        tmp[t] += a;
        __syncthreads();
    }
    loff[t] = tmp[t] - deg;  // exclusive
    int node = (b << 8) + t;
    if (node < n) {
        rbeg[node] = base + loff[t];
        rend[node] = base + loff[t] + deg;
        dinv[node] = rsqrtf((float)(deg + 1));  // +1 self-loop
    }
    __syncthreads();
    for (int idx = t; idx < bsize; idx += 256) {
        unsigned u = bpk[base + idx];
        int ln = (int)(u >> 16);
        int sp = atomicAdd(&lfill[ln], 1);
        scsr[loff[ln] + sp] = (unsigned short)(u & 0xFFFFu);
    }
    __syncthreads();
    for (int idx = t; idx < bsize; idx += 256)
        csr[base + idx] = scsr[idx];
}

// ====== GEMM1 via MFMA bf16x3: hs[n,128] = (x @ W1) * dinv (round-18 verified) ======

__global__ __launch_bounds__(256) void gemm1_k(const float* __restrict__ x,
                                               const unsigned short* __restrict__ wh,
                                               const unsigned short* __restrict__ wl,
                                               const float* __restrict__ dinv,
                                               float* __restrict__ hs, int n) {
    __shared__ __align__(16) unsigned short ah[2 * 8 * 64 * 8];  // 16 KB
    __shared__ __align__(16) unsigned short al[2 * 8 * 64 * 8];  // 16 KB
    __shared__ __align__(16) unsigned short bh[8 * 64 * 8];      // 8 KB
    __shared__ __align__(16) unsigned short bl[8 * 64 * 8];      // 8 KB
    int tid = threadIdx.x;
    int wave = tid >> 6, lane = tid & 63;
    int band = wave & 1, cq = wave >> 1;
    int r0 = blockIdx.x * 32;

    for (int v = tid; v < 2048; v += 256) {
        int r = v >> 6;
        int k = (v & 63) << 2;
        int row = r0 + r;
        if (row >= n) row = n - 1;
        float4 xv = *(const float4*)(x + (long long)row * 256 + k);
        int bd = r >> 4, ks = k >> 5;
        int la = (r & 15) + (((k >> 3) & 3) << 4);
        int i0 = k & 7;
        size_t idx = ((((size_t)bd * 8 + ks) * 64 + la) << 3) + i0;
        ushort4 hh, ll;
        hh.x = f2bf(xv.x); ll.x = f2bf(xv.x - bf2f(hh.x));
        hh.y = f2bf(xv.y); ll.y = f2bf(xv.y - bf2f(hh.y));
        hh.z = f2bf(xv.z); ll.z = f2bf(xv.z - bf2f(hh.z));
        hh.w = f2bf(xv.w); ll.w = f2bf(xv.w - bf2f(hh.w));
        *(ushort4*)&ah[idx] = hh;
        *(ushort4*)&al[idx] = ll;
    }

    f32x4 acc[4];
#pragma unroll
    for (int c = 0; c < 4; ++c) acc[c] = (f32x4){0.f, 0.f, 0.f, 0.f};

    const float4* gh = (const float4*)wh;
    const float4* gl = (const float4*)wl;
    for (int ks = 0; ks < 8; ++ks) {
        __syncthreads();
#pragma unroll
        for (int it = 0; it < 2; ++it) {
            int s = it * 256 + tid;
            size_t gi = ((size_t)(s >> 6) * 8 + ks) * 64 + (s & 63);
            ((float4*)bh)[s] = gh[gi];
            ((float4*)bl)[s] = gl[gi];
        }
        __syncthreads();
        size_t aidx = (((size_t)band * 8 + ks) * 64 + lane) << 3;
        s16x8 Ah = *(const s16x8*)&ah[aidx];
        s16x8 Al = *(const s16x8*)&al[aidx];
#pragma unroll
        for (int c = 0; c < 4; ++c) {
            int ct = cq * 4 + c;
            size_t bidx = (((size_t)ct) * 64 + lane) << 3;
            s16x8 Bh = *(const s16x8*)&bh[bidx];
            s16x8 Bl = *(const s16x8*)&bl[bidx];
            acc[c] = __builtin_amdgcn_mfma_f32_16x16x32_bf16(Ah, Bh, acc[c], 0, 0, 0);
            acc[c] = __builtin_amdgcn_mfma_f32_16x16x32_bf16(Ah, Bl, acc[c], 0, 0, 0);
            acc[c] = __builtin_amdgcn_mfma_f32_16x16x32_bf16(Al, Bh, acc[c], 0, 0, 0);
        }
    }

    int colb = cq * 64 + (lane & 15);
    int rbase = r0 + band * 16 + ((lane >> 4) << 2);
#pragma unroll
    for (int reg = 0; reg < 4; ++reg) {
        int row = rbase + reg;
        if (row < n) {
            float di = dinv[row];
#pragma unroll
            for (int c = 0; c < 4; ++c)
                hs[(long long)row * 128 + colb + c * 16] = acc[c][reg] * di;
        }
    }
}

// ====== GEMM2 (fp32, known-good): hs2[n,64] = (h1 @ W2) * dinv ======
// Logits are threshold-critical -> keep full fp32 path here.

__global__ __launch_bounds__(128) void gemm2_k(const float* __restrict__ h1,
                                               const float* __restrict__ W,
                                               const float* __restrict__ dinv,
                                               float* __restrict__ hs2, int n) {
    __shared__ float xs[32][64];  // 8 KB
    int tid = threadIdx.x;
    int cg = tid & 15;   // cols cg*4 .. +3  (64 cols)
    int rg = tid >> 4;   // rows rg*4 .. +3  (32 rows)
    int r0 = blockIdx.x * 32;
    float acc[4][4];
#pragma unroll
    for (int r = 0; r < 4; ++r)
#pragma unroll
        for (int c = 0; c < 4; ++c) acc[r][c] = 0.0f;

    for (int kc = 0; kc < 2; ++kc) {  // 2 chunks of 64 k
        __syncthreads();
        for (int v = tid; v < 32 * 16; v += 128) {
            int r = v >> 4;
            int k4 = v & 15;
            float4 val = make_float4(0.f, 0.f, 0.f, 0.f);
            int row = r0 + r;
            if (row < n) val = *(const float4*)(h1 + (long long)row * 128 + kc * 64 + k4 * 4);
            *(float4*)&xs[r][k4 * 4] = val;
        }
        __syncthreads();
        const float* Wp = W + (long long)(kc * 64) * 64 + cg * 4;
#pragma unroll 4
        for (int k4 = 0; k4 < 16; ++k4) {
            float4 w0 = *(const float4*)(Wp + (k4 * 4 + 0) * 64);
            float4 w1 = *(const float4*)(Wp + (k4 * 4 + 1) * 64);
            float4 w2 = *(const float4*)(Wp + (k4 * 4 + 2) * 64);
            float4 w3 = *(const float4*)(Wp + (k4 * 4 + 3) * 64);
#pragma unroll
            for (int r = 0; r < 4; ++r) {
                float4 xv = *(const float4*)&xs[rg * 4 + r][k4 * 4];
                acc[r][0] += xv.x * w0.x + xv.y * w1.x + xv.z * w2.x + xv.w * w3.x;
                acc[r][1] += xv.x * w0.y + xv.y * w1.y + xv.z * w2.y + xv.w * w3.y;
                acc[r][2] += xv.x * w0.z + xv.y * w1.z + xv.z * w2.z + xv.w * w3.z;
                acc[r][3] += xv.x * w0.w + xv.y * w1.w + xv.z * w2.w + xv.w * w3.w;
            }
        }
    }
#pragma unroll
    for (int r = 0; r < 4; ++r) {
        int row = r0 + rg * 4 + r;
        if (row < n) {
            float di = dinv[row];
            float4 o = make_float4(acc[r][0] * di, acc[r][1] * di,
                                   acc[r][2] * di, acc[r][3] * di);
            *(float4*)(hs2 + (long long)row * 64 + cg * 4) = o;
        }
    }
}

// ====== channel-split gathers, merged dispatch, LINEAR node order ======
// (degree-sort perm regressed: node-ID order IS the locality order on random graphs)

__global__ void gather1p_k(const float* __restrict__ hs, const int* __restrict__ rbeg,
                           const int* __restrict__ rend, const unsigned short* __restrict__ csr,
                           const float* __restrict__ dinv, const float* __restrict__ b1,
                           float* __restrict__ h1, int n, int gblk) {
    int pass = blockIdx.x / gblk;
    int blk = blockIdx.x - pass * gblk;
    int c0 = pass * 32;
    int g = threadIdx.x >> 3;
    int lane = threadIdx.x & 7;
    int i = blk * 32 + g;
    if (i >= n) return;
    const float* hsc = hs + c0;
    float4 acc = ((const float4*)(hsc + (long long)i * 128))[lane];  // self term
    int beg = rbeg[i], end = rend[i];
    int j = beg;
    for (; j + 8 <= end; j += 8) {
        int s0 = csr[j], s1 = csr[j + 1], s2 = csr[j + 2], s3 = csr[j + 3];
        int s4 = csr[j + 4], s5 = csr[j + 5], s6 = csr[j + 6], s7 = csr[j + 7];
        float4 v0 = ((const float4*)(hsc + (long long)s0 * 128))[lane];
        float4 v1 = ((const float4*)(hsc + (long long)s1 * 128))[lane];
        float4 v2 = ((const float4*)(hsc + (long long)s2 * 128))[lane];
        float4 v3 = ((const float4*)(hsc + (long long)s3 * 128))[lane];
        float4 v4 = ((const float4*)(hsc + (long long)s4 * 128))[lane];
        float4 v5 = ((const float4*)(hsc + (long long)s5 * 128))[lane];
        float4 v6 = ((const float4*)(hsc + (long long)s6 * 128))[lane];
        float4 v7 = ((const float4*)(hsc + (long long)s7 * 128))[lane];
        acc.x += (v0.x + v1.x + v2.x + v3.x) + (v4.x + v5.x + v6.x + v7.x);
        acc.y += (v0.y + v1.y + v2.y + v3.y) + (v4.y + v5.y + v6.y + v7.y);
        acc.z += (v0.z + v1.z + v2.z + v3.z) + (v4.z + v5.z + v6.z + v7.z);
        acc.w += (v0.w + v1.w + v2.w + v3.w) + (v4.w + v5.w + v6.w + v7.w);
    }
    for (; j < end; ++j) {
        int s0 = csr[j];
        float4 v0 = ((const float4*)(hsc + (long long)s0 * 128))[lane];
        acc.x += v0.x; acc.y += v0.y; acc.z += v0.z; acc.w += v0.w;
    }
    float di = dinv[i];
    float4 bb = ((const float4*)(b1 + c0))[lane];
    float4 o;
    o.x = fmaxf(di * acc.x + bb.x, 0.0f);
    o.y = fmaxf(di * acc.y + bb.y, 0.0f);
    o.z = fmaxf(di * acc.z + bb.z, 0.0f);
    o.w = fmaxf(di * acc.w + bb.w, 0.0f);
    ((float4*)(h1 + (long long)i * 128 + c0))[lane] = o;
}

__global__ void gather2p_k(const float* __restrict__ hs2, const int* __restrict__ rbeg,
                           const int* __restrict__ rend, const unsigned short* __restrict__ csr,
                           const float* __restrict__ dinv, const float* __restrict__ b2,
                           float* __restrict__ out, int n, int gblk) {
    int pass = blockIdx.x / gblk;
    int blk = blockIdx.x - pass * gblk;
    int c0 = pass * 32;
    int g = threadIdx.x >> 3;
    int lane = threadIdx.x & 7;
    int i = blk * 32 + g;
    if (i >= n) return;
    const float* hc = hs2 + c0;
    float4 acc = ((const float4*)(hc + (long long)i * 64))[lane];  // self term
    int beg = rbeg[i], end = rend[i];
    int j = beg;
    for (; j + 8 <= end; j += 8) {
        int s0 = csr[j], s1 = csr[j + 1], s2 = csr[j + 2], s3 = csr[j + 3];
        int s4 = csr[j + 4], s5 = csr[j + 5], s6 = csr[j + 6], s7 = csr[j + 7];
        float4 v0 = ((const float4*)(hc + (long long)s0 * 64))[lane];
        float4 v1 = ((const float4*)(hc + (long long)s1 * 64))[lane];
        float4 v2 = ((const float4*)(hc + (long long)s2 * 64))[lane];
        float4 v3 = ((const float4*)(hc + (long long)s3 * 64))[lane];
        float4 v4 = ((const float4*)(hc + (long long)s4 * 64))[lane];
        float4 v5 = ((const float4*)(hc + (long long)s5 * 64))[lane];
        float4 v6 = ((const float4*)(hc + (long long)s6 * 64))[lane];
        float4 v7 = ((const float4*)(hc + (long long)s7 * 64))[lane];
        acc.x += (v0.x + v1.x + v2.x + v3.x) + (v4.x + v5.x + v6.x + v7.x);
        acc.y += (v0.y + v1.y + v2.y + v3.y) + (v4.y + v5.y + v6.y + v7.y);
        acc.z += (v0.z + v1.z + v2.z + v3.z) + (v4.z + v5.z + v6.z + v7.z);
        acc.w += (v0.w + v1.w + v2.w + v3.w) + (v4.w + v5.w + v6.w + v7.w);
    }
    for (; j < end; ++j) {
        int s0 = csr[j];
        float4 v0 = ((const float4*)(hc + (long long)s0 * 64))[lane];
        acc.x += v0.x; acc.y += v0.y; acc.z += v0.z; acc.w += v0.w;
    }
    float di = dinv[i];
    float4 bb = ((const float4*)(b2 + c0))[lane];
    float lx = di * acc.x + bb.x;
    float ly = di * acc.y + bb.y;
    float lz = di * acc.z + bb.z;
    float lw = di * acc.w + bb.w;
    float4 p;
    p.x = 1.0f / (1.0f + expf(-lx));
    p.y = 1.0f / (1.0f + expf(-ly));
    p.z = 1.0f / (1.0f + expf(-lz));
    p.w = 1.0f / (1.0f + expf(-lw));
    long long total = (long long)n * 64;
    long long o0 = (long long)i * 64 + c0 + lane * 4;
    float4 pr;
    pr.x = (p.x > 0.5f) ? 1.0f : 0.0f;
    pr.y = (p.y > 0.5f) ? 1.0f : 0.0f;
    pr.z = (p.z > 0.5f) ? 1.0f : 0.0f;
    pr.w = (p.w > 0.5f) ? 1.0f : 0.0f;
    *(float4*)(out + o0) = pr;
    *(float4*)(out + total + o0) = p;
}

// ================= launch =================

extern "C" void kernel_launch(void* const* d_in, const int* in_sizes, int n_in,
                              void* d_out, int out_size, void* d_ws, size_t ws_size,
                              hipStream_t stream) {
    const float* x  = (const float*)d_in[0];
    const int*   ei = (const int*)d_in[1];
    const float* W1 = (const float*)d_in[2];
    const float* b1 = (const float*)d_in[3];
    const float* W2 = (const float*)d_in[4];
    const float* b2 = (const float*)d_in[5];
    float* out = (float*)d_out;

    const int n = in_sizes[0] / 256;   // 50000 (packing requires n < 65536)
    const int E = in_sizes[1] / 2;     // 1.6M
    const int* src = ei;
    const int* dst = ei + E;
    const int nb = (n + 255) / 256;    // bucket count (196)

    // ---- workspace carve-up (256B-aligned) ----
    char* base = (char*)d_ws;
    size_t off = 0;
    auto carve = [&](size_t bytes) -> void* {
        void* p = base + off;
        off = (off + bytes + 255) & ~(size_t)255;
        return p;
    };
    int*   bfill = (int*)  carve(256 * sizeof(int));
    unsigned short* csr = (unsigned short*)carve((size_t)nb * CAP * sizeof(unsigned short));
    int*   rbeg  = (int*)  carve((size_t)n * sizeof(int));
    int*   rend  = (int*)  carve((size_t)n * sizeof(int));
    float* dinv  = (float*)carve((size_t)n * sizeof(float));
    unsigned short* w1h = (unsigned short*)carve(32768 * sizeof(unsigned short));
    unsigned short* w1l = (unsigned short*)carve(32768 * sizeof(unsigned short));
    float* hs0   = (float*)carve((size_t)n * 128 * sizeof(float));
    float* h1    = (float*)carve((size_t)n * 128 * sizeof(float));
    float* hs2   = (float*)carve((size_t)n * 64 * sizeof(float));
    // packed bucket buffer aliases hs0 (nb*CAP*4B = 9.6MB <= 25.6MB);
    // consumed by bucket_build_k before gemm1_k writes hs0 (same stream, sequential)
    unsigned int* bpk = (unsigned int*)hs0;

    const int SB = (E + CHUNK - 1) / CHUNK;  // scatter blocks (391)
    const int PB = 32768 / 256;              // W1 pack blocks (128)

    hipMemsetAsync(bfill, 0, 256 * sizeof(int), stream);
    prep_k<<<SB + PB, 256, 0, stream>>>(src, dst, bfill, bpk, E, SB, W1, w1h, w1l);
    bucket_build_k<<<nb, 256, 0, stream>>>(bpk, bfill, csr, rbeg, rend, dinv, n);

    gemm1_k<<<(n + 31) / 32, 256, 0, stream>>>(x, w1h, w1l, dinv, hs0, n);

    const int gblk = (n + 31) / 32;
    gather1p_k<<<4 * gblk, 256, 0, stream>>>(hs0, rbeg, rend, csr, dinv, b1, h1, n, gblk);

    gemm2_k<<<(n + 31) / 32, 128, 0, stream>>>(h1, W2, dinv, hs2, n);

    gather2p_k<<<2 * gblk, 256, 0, stream>>>(hs2, rbeg, rend, csr, dinv, b2, out, n, gblk);
}